// Round 1
// baseline (273.615 us; speedup 1.0000x reference)
//
#include <hip/hip_runtime.h>
#include <hip/hip_bf16.h>
#include <stdint.h>

// Problem constants (MultiHeadAttention: B=2, S=2048, H=16, Dk=Dv=64, Dm=1024)
#define BATCH 2
#define SEQ   2048
#define NH    16
#define DH    64
#define DM    1024
#define MR    (BATCH * SEQ)   // 4096 rows

typedef __bf16 bf16_t;
typedef bf16_t bf16x8 __attribute__((ext_vector_type(8)));
typedef float  f32x4  __attribute__((ext_vector_type(4)));

typedef const __attribute__((address_space(1))) void* gas_t;
typedef       __attribute__((address_space(3))) void* las_t;

// async global->LDS, 16B per lane; LDS dest is wave-uniform base + lane*16
__device__ __forceinline__ void gload16(const void* g, void* l) {
  __builtin_amdgcn_global_load_lds((gas_t)g, (las_t)l, 16, 0, 0);
}

// ---------------- fp32 -> bf16 elementwise ----------------
__global__ __launch_bounds__(256) void cvt_kernel(const float* __restrict__ x,
                                                  bf16_t* __restrict__ y, int n) {
  int i = (blockIdx.x * 256 + threadIdx.x) * 8;
  if (i + 8 <= n) {
    float4 a = *(const float4*)(x + i);
    float4 b = *(const float4*)(x + i + 4);
    bf16x8 o;
    o[0] = (bf16_t)a.x; o[1] = (bf16_t)a.y; o[2] = (bf16_t)a.z; o[3] = (bf16_t)a.w;
    o[4] = (bf16_t)b.x; o[5] = (bf16_t)b.y; o[6] = (bf16_t)b.z; o[7] = (bf16_t)b.w;
    *(bf16x8*)(y + i) = o;
  }
}

// ---------------- W (KxN f32) -> Wt (NxK bf16), tiled transpose ----------------
__global__ __launch_bounds__(256) void wtrans_kernel(const float* __restrict__ W,
                                                     bf16_t* __restrict__ Wt) {
  __shared__ bf16_t t[64][65];
  const int c0 = blockIdx.x * 64, r0 = blockIdx.y * 64;
  const int tid = threadIdx.x;
  const int r = tid >> 2, cc = (tid & 3) * 16;
  const float* src = W + (size_t)(r0 + r) * DM + c0 + cc;
#pragma unroll
  for (int i = 0; i < 16; ++i) t[r][cc + i] = (bf16_t)src[i];
  __syncthreads();
  bf16_t* dst = Wt + (size_t)(c0 + r) * DM + r0 + cc;
#pragma unroll
  for (int i = 0; i < 16; ++i) dst[i] = t[cc + i][r];
}

// ---------------- v (MR x DM) -> vT (per (b,h): DH x SEQ) ----------------
__global__ __launch_bounds__(256) void vtrans_kernel(const bf16_t* __restrict__ v,
                                                     bf16_t* __restrict__ vT) {
  __shared__ bf16_t t[64][65];
  const int s0 = blockIdx.x * 64;
  const int h = blockIdx.y, b = blockIdx.z;
  const int tid = threadIdx.x;
  const int r = tid >> 2, cc = (tid & 3) * 16;
  const bf16_t* src = v + (size_t)(b * SEQ + s0 + r) * DM + h * DH + cc;
#pragma unroll
  for (int i = 0; i < 16; ++i) t[r][cc + i] = src[i];
  __syncthreads();
  bf16_t* dst = vT + (size_t)((b * NH + h) * DH + r) * SEQ + s0 + cc;
#pragma unroll
  for (int i = 0; i < 16; ++i) dst[i] = t[cc + i][r];
}

// ---------------- GEMM: C(MxN) = A(MxK) @ Bt(NxK)^T + bias ----------------
// 128x128 tile, BK=64, 4 waves (2x2), 16x16x32 bf16 MFMA, global_load_lds w=16,
// XOR swizzle (chunk j ^= row&7 within 128B rows) -> conflict-free ds_read_b128.
template <int OUT_BF16>
__global__ __launch_bounds__(256) void gemm_kernel(const bf16_t* __restrict__ A,
                                                   const bf16_t* __restrict__ Bt,
                                                   const float* __restrict__ bias,
                                                   void* __restrict__ Cv,
                                                   int K, int N) {
  __shared__ __attribute__((aligned(16))) bf16_t As[128 * 64];
  __shared__ __attribute__((aligned(16))) bf16_t Bs[128 * 64];
  const int m0 = blockIdx.x * 128, n0 = blockIdx.y * 128;
  const int tid = threadIdx.x;
  const int wave = tid >> 6, lane = tid & 63;
  const int lm = lane & 15, lg = lane >> 4;
  const int wr = wave >> 1, wc = wave & 1;
  f32x4 acc[4][4];
#pragma unroll
  for (int a = 0; a < 4; ++a)
#pragma unroll
    for (int bb = 0; bb < 4; ++bb) acc[a][bb] = (f32x4){0.f, 0.f, 0.f, 0.f};

  for (int k0 = 0; k0 < K; k0 += 64) {
    __syncthreads();
#pragma unroll
    for (int i = 0; i < 4; ++i) {
      const int c = tid + i * 256;          // chunk id: row = c>>3, j = c&7
      const int row = c >> 3, j = c & 7, js = j ^ (row & 7);
      gload16(A  + (size_t)(m0 + row) * K + k0 + js * 8,
              As + (size_t)(wave * 64 + i * 256) * 8);
      gload16(Bt + (size_t)(n0 + row) * K + k0 + js * 8,
              Bs + (size_t)(wave * 64 + i * 256) * 8);
    }
    asm volatile("s_waitcnt vmcnt(0)" ::: "memory");
    __syncthreads();
#pragma unroll
    for (int kk = 0; kk < 2; ++kk) {
      bf16x8 af[4], bfr[4];
#pragma unroll
      for (int t = 0; t < 4; ++t) {
        const int ra = wr * 64 + t * 16 + lm;
        af[t] = *(const bf16x8*)((const char*)As + ra * 128 +
                                 ((kk * 64 + lg * 16) ^ ((ra & 7) << 4)));
        const int rb = wc * 64 + t * 16 + lm;
        bfr[t] = *(const bf16x8*)((const char*)Bs + rb * 128 +
                                  ((kk * 64 + lg * 16) ^ ((rb & 7) << 4)));
      }
#pragma unroll
      for (int mf = 0; mf < 4; ++mf)
#pragma unroll
        for (int nf = 0; nf < 4; ++nf)
          acc[mf][nf] = __builtin_amdgcn_mfma_f32_16x16x32_bf16(af[mf], bfr[nf],
                                                                acc[mf][nf], 0, 0, 0);
    }
  }
  // epilogue: D layout col = lane&15, row = (lane>>4)*4 + i   [m89 verified]
#pragma unroll
  for (int mf = 0; mf < 4; ++mf)
#pragma unroll
    for (int nf = 0; nf < 4; ++nf) {
      const int col = n0 + wc * 64 + nf * 16 + lm;
      const float bv = bias[col];
#pragma unroll
      for (int i = 0; i < 4; ++i) {
        const int row = m0 + wr * 64 + mf * 16 + lg * 4 + i;
        const float val = acc[mf][nf][i] + bv;
        if (OUT_BF16) ((bf16_t*)Cv)[(size_t)row * N + col] = (bf16_t)val;
        else          ((float*)Cv)[(size_t)row * N + col] = val;
      }
    }
}

// ---------------- flash attention ----------------
// grid (SEQ/128, NH, BATCH); 4 waves; wave owns 32 q-rows; KV tiles of 64.
// Q,K tiles [rows][64d], V tile transposed [64d][64krow]; all rows are 128B ->
// XOR swizzle everywhere. P goes D-layout -> (swizzled LDS) -> A-layout.
__global__ __launch_bounds__(256) void flash_kernel(const bf16_t* __restrict__ q,
                                                    const bf16_t* __restrict__ k,
                                                    const bf16_t* __restrict__ vT,
                                                    bf16_t* __restrict__ o) {
  __shared__ __attribute__((aligned(16))) bf16_t Qs[128 * 64];
  __shared__ __attribute__((aligned(16))) bf16_t Ks[64 * 64];
  __shared__ __attribute__((aligned(16))) bf16_t Vs[64 * 64];   // [d][krow]
  __shared__ __attribute__((aligned(16))) bf16_t Ps[4 * 32 * 64];
  const int qt = blockIdx.x, h = blockIdx.y, b = blockIdx.z;
  const int tid = threadIdx.x;
  const int wave = tid >> 6, lane = tid & 63;
  const int lm = lane & 15, lg = lane >> 4;

  // stage Q once (1024 chunks, 4/thread), pre-swizzled source
#pragma unroll
  for (int i = 0; i < 4; ++i) {
    const int c = tid + i * 256;
    const int row = c >> 3, j = c & 7, js = j ^ (row & 7);
    gload16(q + (size_t)(b * SEQ + qt * 128 + row) * DM + h * DH + js * 8,
            Qs + (size_t)(wave * 64 + i * 256) * 8);
  }
  asm volatile("s_waitcnt vmcnt(0)" ::: "memory");
  __syncthreads();

  // Q fragments held in registers for the whole KV loop
  bf16x8 qf[2][2];
#pragma unroll
  for (int mf = 0; mf < 2; ++mf)
#pragma unroll
    for (int kk = 0; kk < 2; ++kk) {
      const int row = wave * 32 + mf * 16 + lm;
      qf[mf][kk] = *(const bf16x8*)((const char*)Qs + row * 128 +
                                    ((kk * 64 + lg * 16) ^ ((row & 7) << 4)));
    }

  f32x4 acc[2][4];
  float mrun[2][4], lrun[2][4];
#pragma unroll
  for (int mf = 0; mf < 2; ++mf)
#pragma unroll
    for (int i = 0; i < 4; ++i) { mrun[mf][i] = -1e30f; lrun[mf][i] = 0.f; }
#pragma unroll
  for (int mf = 0; mf < 2; ++mf)
#pragma unroll
    for (int nf = 0; nf < 4; ++nf) acc[mf][nf] = (f32x4){0.f, 0.f, 0.f, 0.f};

  for (int kt = 0; kt < SEQ / 64; ++kt) {
    __syncthreads();   // previous iteration's K/V reads done
#pragma unroll
    for (int i = 0; i < 2; ++i) {
      const int c = tid + i * 256;
      const int row = c >> 3, j = c & 7, js = j ^ (row & 7);
      gload16(k + (size_t)(b * SEQ + kt * 64 + row) * DM + h * DH + js * 8,
              Ks + (size_t)(wave * 64 + i * 256) * 8);
      gload16(vT + (size_t)((b * NH + h) * DH + row) * SEQ + kt * 64 + js * 8,
              Vs + (size_t)(wave * 64 + i * 256) * 8);
    }
    asm volatile("s_waitcnt vmcnt(0)" ::: "memory");
    __syncthreads();

    // ---- QK^T: S(32q x 64k) per wave ----
    f32x4 sc[2][4];
#pragma unroll
    for (int mf = 0; mf < 2; ++mf)
#pragma unroll
      for (int nf = 0; nf < 4; ++nf) sc[mf][nf] = (f32x4){0.f, 0.f, 0.f, 0.f};
#pragma unroll
    for (int kk = 0; kk < 2; ++kk) {
      bf16x8 kf[4];
#pragma unroll
      for (int nf = 0; nf < 4; ++nf) {
        const int row = nf * 16 + lm;   // k-row acts as MFMA N index
        kf[nf] = *(const bf16x8*)((const char*)Ks + row * 128 +
                                  ((kk * 64 + lg * 16) ^ ((row & 7) << 4)));
      }
#pragma unroll
      for (int mf = 0; mf < 2; ++mf)
#pragma unroll
        for (int nf = 0; nf < 4; ++nf)
          sc[mf][nf] = __builtin_amdgcn_mfma_f32_16x16x32_bf16(qf[mf][kk], kf[nf],
                                                               sc[mf][nf], 0, 0, 0);
    }
#pragma unroll
    for (int mf = 0; mf < 2; ++mf)
#pragma unroll
      for (int nf = 0; nf < 4; ++nf) sc[mf][nf] *= 0.125f;  // 1/sqrt(64)

    // ---- online softmax (rows replicated across each 16-lane group) ----
#pragma unroll
    for (int mf = 0; mf < 2; ++mf)
#pragma unroll
      for (int i = 0; i < 4; ++i) {
        float rm = fmaxf(fmaxf(sc[mf][0][i], sc[mf][1][i]),
                         fmaxf(sc[mf][2][i], sc[mf][3][i]));
#pragma unroll
        for (int d = 1; d < 16; d <<= 1) rm = fmaxf(rm, __shfl_xor(rm, d));
        const float mn = fmaxf(mrun[mf][i], rm);
        const float alpha = __expf(mrun[mf][i] - mn);
        mrun[mf][i] = mn;
        float s0 = 0.f;
#pragma unroll
        for (int nf = 0; nf < 4; ++nf) {
          const float p = __expf(sc[mf][nf][i] - mn);
          sc[mf][nf][i] = p;
          s0 += p;
        }
#pragma unroll
        for (int d = 1; d < 16; d <<= 1) s0 += __shfl_xor(s0, d);
        lrun[mf][i] = lrun[mf][i] * alpha + s0;
#pragma unroll
        for (int nf = 0; nf < 4; ++nf) acc[mf][nf][i] *= alpha;
      }

    // ---- P: D-layout regs -> swizzled per-wave LDS (bf16) ----
#pragma unroll
    for (int mf = 0; mf < 2; ++mf)
#pragma unroll
      for (int nf = 0; nf < 4; ++nf)
#pragma unroll
        for (int i = 0; i < 4; ++i) {
          const int r = mf * 16 + lg * 4 + i;          // q-row in wave tile
          const int cbyte = (nf * 16 + lm) * 2;        // k-col byte
          *(bf16_t*)((char*)Ps + wave * 4096 + r * 128 +
                     (cbyte ^ ((r & 7) << 4))) = (bf16_t)sc[mf][nf][i];
        }

    // ---- PV: O(32q x 64d) += P(32x64) @ V(64x64) ----
#pragma unroll
    for (int kk = 0; kk < 2; ++kk) {
      bf16x8 pf[2], vf[4];
#pragma unroll
      for (int mf = 0; mf < 2; ++mf) {
        const int r = mf * 16 + lm;                    // A-layout row = lane&15
        pf[mf] = *(const bf16x8*)((const char*)Ps + wave * 4096 + r * 128 +
                                  ((kk * 64 + lg * 16) ^ ((r & 7) << 4)));
      }
#pragma unroll
      for (int nf = 0; nf < 4; ++nf) {
        const int r = nf * 16 + lm;                    // d-row in Vs
        vf[nf] = *(const bf16x8*)((const char*)Vs + r * 128 +
                                  ((kk * 64 + lg * 16) ^ ((r & 7) << 4)));
      }
#pragma unroll
      for (int mf = 0; mf < 2; ++mf)
#pragma unroll
        for (int nf = 0; nf < 4; ++nf)
          acc[mf][nf] = __builtin_amdgcn_mfma_f32_16x16x32_bf16(pf[mf], vf[nf],
                                                                acc[mf][nf], 0, 0, 0);
    }
  }

  // ---- epilogue: O /= l, store bf16 ----
#pragma unroll
  for (int mf = 0; mf < 2; ++mf)
#pragma unroll
    for (int i = 0; i < 4; ++i) {
      const float inv = 1.f / lrun[mf][i];
      const int row = b * SEQ + qt * 128 + wave * 32 + mf * 16 + lg * 4 + i;
#pragma unroll
      for (int nf = 0; nf < 4; ++nf) {
        const int col = h * DH + nf * 16 + lm;
        o[(size_t)row * DM + col] = (bf16_t)(acc[mf][nf][i] * inv);
      }
    }
}

extern "C" void kernel_launch(void* const* d_in, const int* in_sizes, int n_in,
                              void* d_out, int out_size, void* d_ws, size_t ws_size,
                              hipStream_t stream) {
  (void)in_sizes; (void)n_in; (void)out_size; (void)ws_size;
  const float* Q  = (const float*)d_in[0];
  const float* Kx = (const float*)d_in[1];
  const float* V  = (const float*)d_in[2];
  const float* WQ = (const float*)d_in[3];
  const float* bQ = (const float*)d_in[4];
  const float* WK = (const float*)d_in[5];
  const float* bK = (const float*)d_in[6];
  const float* WV = (const float*)d_in[7];
  const float* bV = (const float*)d_in[8];
  const float* WO = (const float*)d_in[9];
  const float* bO = (const float*)d_in[10];

  const size_t MS  = (size_t)MR * DM;   // 4M elements
  const size_t WSZ = (size_t)DM * DM;   // 1M elements
  bf16_t* ws  = (bf16_t*)d_ws;          // total use: 6*MS + 4*WSZ elems (~56 MB)
  bf16_t* Qb  = ws;
  bf16_t* Kb  = Qb + MS;
  bf16_t* Vb  = Kb + MS;
  bf16_t* WQt = Vb + MS;
  bf16_t* WKt = WQt + WSZ;
  bf16_t* WVt = WKt + WSZ;
  bf16_t* WOt = WVt + WSZ;
  bf16_t* qp  = WOt + WSZ;
  bf16_t* kp  = qp + MS;
  bf16_t* vp  = kp + MS;
  bf16_t* vTb = Qb;   // alias: Qb dead after q projection
  bf16_t* ao  = Kb;   // alias: Kb dead after k projection

  cvt_kernel<<<dim3((unsigned)(MS / 2048)), 256, 0, stream>>>(Q,  Qb, (int)MS);
  cvt_kernel<<<dim3((unsigned)(MS / 2048)), 256, 0, stream>>>(Kx, Kb, (int)MS);
  cvt_kernel<<<dim3((unsigned)(MS / 2048)), 256, 0, stream>>>(V,  Vb, (int)MS);
  wtrans_kernel<<<dim3(16, 16), 256, 0, stream>>>(WQ, WQt);
  wtrans_kernel<<<dim3(16, 16), 256, 0, stream>>>(WK, WKt);
  wtrans_kernel<<<dim3(16, 16), 256, 0, stream>>>(WV, WVt);
  wtrans_kernel<<<dim3(16, 16), 256, 0, stream>>>(WO, WOt);

  gemm_kernel<1><<<dim3(MR / 128, DM / 128), 256, 0, stream>>>(Qb, WQt, bQ, qp, DM, DM);
  gemm_kernel<1><<<dim3(MR / 128, DM / 128), 256, 0, stream>>>(Kb, WKt, bK, kp, DM, DM);
  gemm_kernel<1><<<dim3(MR / 128, DM / 128), 256, 0, stream>>>(Vb, WVt, bV, vp, DM, DM);

  vtrans_kernel<<<dim3(SEQ / 64, NH, BATCH), 256, 0, stream>>>(vp, vTb);
  flash_kernel<<<dim3(SEQ / 128, NH, BATCH), 256, 0, stream>>>(qp, kp, vTb, ao);
  gemm_kernel<0><<<dim3(MR / 128, DM / 128), 256, 0, stream>>>(ao, WOt, bO, d_out, DM, DM);
}

// Round 4
// 272.538 us; speedup vs baseline: 1.0040x; 1.0040x over previous
//
#include <hip/hip_runtime.h>
#include <hip/hip_bf16.h>
#include <stdint.h>

// Problem constants (MultiHeadAttention: B=2, S=2048, H=16, Dk=Dv=64, Dm=1024)
#define BATCH 2
#define SEQ   2048
#define NH    16
#define DH    64
#define DM    1024
#define MR    (BATCH * SEQ)   // 4096 rows

typedef __bf16 bf16_t;
typedef bf16_t bf16x8 __attribute__((ext_vector_type(8)));
typedef float  f32x4  __attribute__((ext_vector_type(4)));

typedef const __attribute__((address_space(1))) void* gas_t;
typedef       __attribute__((address_space(3))) void* las_t;

__device__ __forceinline__ void gload16(const void* g, void* l) {
  __builtin_amdgcn_global_load_lds((gas_t)g, (las_t)l, 16, 0, 0);
}

__device__ __forceinline__ float fast_exp2(float x) {
#if __has_builtin(__builtin_amdgcn_exp2f)
  return __builtin_amdgcn_exp2f(x);
#else
  float r; asm volatile("v_exp_f32 %0, %1\n\ts_nop 1" : "=v"(r) : "v"(x)); return r;
#endif
}

// ---------------- fp32 -> bf16 elementwise ----------------
__global__ __launch_bounds__(256) void cvt_kernel(const float* __restrict__ x,
                                                  bf16_t* __restrict__ y, int n) {
  int i = (blockIdx.x * 256 + threadIdx.x) * 8;
  if (i + 8 <= n) {
    float4 a = *(const float4*)(x + i);
    float4 b = *(const float4*)(x + i + 4);
    bf16x8 o;
    o[0] = (bf16_t)a.x; o[1] = (bf16_t)a.y; o[2] = (bf16_t)a.z; o[3] = (bf16_t)a.w;
    o[4] = (bf16_t)b.x; o[5] = (bf16_t)b.y; o[6] = (bf16_t)b.z; o[7] = (bf16_t)b.w;
    *(bf16x8*)(y + i) = o;
  }
}

// ---------------- W (KxN f32) -> Wt (NxK bf16), tiled transpose ----------------
__global__ __launch_bounds__(256) void wtrans_kernel(const float* __restrict__ W,
                                                     bf16_t* __restrict__ Wt) {
  __shared__ bf16_t t[64][65];
  const int c0 = blockIdx.x * 64, r0 = blockIdx.y * 64;
  const int tid = threadIdx.x;
  const int r = tid >> 2, cc = (tid & 3) * 16;
  const float* src = W + (size_t)(r0 + r) * DM + c0 + cc;
#pragma unroll
  for (int i = 0; i < 16; ++i) t[r][cc + i] = (bf16_t)src[i];
  __syncthreads();
  bf16_t* dst = Wt + (size_t)(c0 + r) * DM + r0 + cc;
#pragma unroll
  for (int i = 0; i < 16; ++i) dst[i] = t[cc + i][r];
}

// ---------------- v (MR x DM) -> vT (per (b,h): DH x SEQ) ----------------
__global__ __launch_bounds__(256) void vtrans_kernel(const bf16_t* __restrict__ v,
                                                     bf16_t* __restrict__ vT) {
  __shared__ bf16_t t[64][65];
  const int s0 = blockIdx.x * 64;
  const int h = blockIdx.y, b = blockIdx.z;
  const int tid = threadIdx.x;
  const int r = tid >> 2, cc = (tid & 3) * 16;
  const bf16_t* src = v + (size_t)(b * SEQ + s0 + r) * DM + h * DH + cc;
#pragma unroll
  for (int i = 0; i < 16; ++i) t[r][cc + i] = src[i];
  __syncthreads();
  bf16_t* dst = vT + (size_t)((b * NH + h) * DH + r) * SEQ + s0 + cc;
#pragma unroll
  for (int i = 0; i < 16; ++i) dst[i] = t[cc + i][r];
}

// ---------------- GEMM: C(MxN) = (A(MxK) @ Bt(NxK)^T + bias) * scale ----------------
template <int OUT_BF16>
__global__ __launch_bounds__(256) void gemm_kernel(const bf16_t* __restrict__ A,
                                                   const bf16_t* __restrict__ Bt,
                                                   const float* __restrict__ bias,
                                                   float scale,
                                                   void* __restrict__ Cv,
                                                   int K, int N) {
  __shared__ __attribute__((aligned(16))) bf16_t As[128 * 64];
  __shared__ __attribute__((aligned(16))) bf16_t Bs[128 * 64];
  const int m0 = blockIdx.x * 128, n0 = blockIdx.y * 128;
  const int tid = threadIdx.x;
  const int wave = tid >> 6, lane = tid & 63;
  const int lm = lane & 15, lg = lane >> 4;
  const int wr = wave >> 1, wc = wave & 1;
  f32x4 acc[4][4];
#pragma unroll
  for (int a = 0; a < 4; ++a)
#pragma unroll
    for (int bb = 0; bb < 4; ++bb) acc[a][bb] = (f32x4){0.f, 0.f, 0.f, 0.f};

  for (int k0 = 0; k0 < K; k0 += 64) {
    __syncthreads();
#pragma unroll
    for (int i = 0; i < 4; ++i) {
      const int c = tid + i * 256;          // chunk id: row = c>>3, j = c&7
      const int row = c >> 3, j = c & 7, js = j ^ (row & 7);
      gload16(A  + (size_t)(m0 + row) * K + k0 + js * 8,
              As + (size_t)(wave * 64 + i * 256) * 8);
      gload16(Bt + (size_t)(n0 + row) * K + k0 + js * 8,
              Bs + (size_t)(wave * 64 + i * 256) * 8);
    }
    asm volatile("s_waitcnt vmcnt(0)" ::: "memory");
    __syncthreads();
#pragma unroll
    for (int kk = 0; kk < 2; ++kk) {
      bf16x8 af[4], bfr[4];
#pragma unroll
      for (int t = 0; t < 4; ++t) {
        const int ra = wr * 64 + t * 16 + lm;
        af[t] = *(const bf16x8*)((const char*)As + ra * 128 +
                                 ((kk * 64 + lg * 16) ^ ((ra & 7) << 4)));
        const int rb = wc * 64 + t * 16 + lm;
        bfr[t] = *(const bf16x8*)((const char*)Bs + rb * 128 +
                                  ((kk * 64 + lg * 16) ^ ((rb & 7) << 4)));
      }
#pragma unroll
      for (int mf = 0; mf < 4; ++mf)
#pragma unroll
        for (int nf = 0; nf < 4; ++nf)
          acc[mf][nf] = __builtin_amdgcn_mfma_f32_16x16x32_bf16(af[mf], bfr[nf],
                                                                acc[mf][nf], 0, 0, 0);
    }
  }
#pragma unroll
  for (int mf = 0; mf < 4; ++mf)
#pragma unroll
    for (int nf = 0; nf < 4; ++nf) {
      const int col = n0 + wc * 64 + nf * 16 + lm;
      const float bv = bias[col];
#pragma unroll
      for (int i = 0; i < 4; ++i) {
        const int row = m0 + wr * 64 + mf * 16 + lg * 4 + i;
        const float val = (acc[mf][nf][i] + bv) * scale;
        if (OUT_BF16) ((bf16_t*)Cv)[(size_t)row * N + col] = (bf16_t)val;
        else          ((float*)Cv)[(size_t)row * N + col] = val;
      }
    }
}

// ---------------- flash attention (barrier-free, L2-direct K/V) ----------------
// 1-D grid of 512, XCD-swizzled. 4 waves/block, wave owns 32 q rows.
// K/V per (b,h) = 512 KB -> L2 resident; fragments loaded straight from global.
// Only LDS use: per-wave P round-trip (no barriers anywhere in the KV loop).
// q comes pre-scaled by 0.125*log2(e) -> softmax in exp2 domain.
typedef struct { bf16x8 f[2][4]; } Frags;   // [kk][nf]

__device__ __forceinline__ void load_kf(Frags& kf, const bf16_t* __restrict__ kb,
                                        int kt, int lm, int lg) {
#pragma unroll
  for (int kk = 0; kk < 2; ++kk)
#pragma unroll
    for (int nf = 0; nf < 4; ++nf)
      kf.f[kk][nf] = *(const bf16x8*)(kb + (size_t)(kt * 64 + nf * 16 + lm) * DM +
                                      kk * 32 + lg * 8);
}

__device__ __forceinline__ void load_vf(Frags& vf, const bf16_t* __restrict__ vb,
                                        int kt, int lm, int lg) {
#pragma unroll
  for (int kk = 0; kk < 2; ++kk)
#pragma unroll
    for (int nf = 0; nf < 4; ++nf)
      vf.f[kk][nf] = *(const bf16x8*)(vb + (size_t)(nf * 16 + lm) * SEQ +
                                      kt * 64 + kk * 32 + lg * 8);
}

__device__ __forceinline__ void attn_iter(const Frags& kf, const Frags& vf,
                                          const bf16x8 (&qf)[2][2],
                                          f32x4 (&acc)[2][4],
                                          float (&mrun)[2][4], float (&lrun)[2][4],
                                          char* __restrict__ PsW, int lm, int lg) {
  // ---- QK^T ----
  f32x4 sc[2][4];
#pragma unroll
  for (int mf = 0; mf < 2; ++mf)
#pragma unroll
    for (int nf = 0; nf < 4; ++nf) sc[mf][nf] = (f32x4){0.f, 0.f, 0.f, 0.f};
#pragma unroll
  for (int kk = 0; kk < 2; ++kk)
#pragma unroll
    for (int mf = 0; mf < 2; ++mf)
#pragma unroll
      for (int nf = 0; nf < 4; ++nf)
        sc[mf][nf] = __builtin_amdgcn_mfma_f32_16x16x32_bf16(qf[mf][kk], kf.f[kk][nf],
                                                             sc[mf][nf], 0, 0, 0);
  // ---- online softmax (exp2 domain; q pre-scaled) ----
#pragma unroll
  for (int mf = 0; mf < 2; ++mf)
#pragma unroll
    for (int i = 0; i < 4; ++i) {
      float rm = fmaxf(fmaxf(sc[mf][0][i], sc[mf][1][i]),
                       fmaxf(sc[mf][2][i], sc[mf][3][i]));
#pragma unroll
      for (int d = 1; d < 16; d <<= 1) rm = fmaxf(rm, __shfl_xor(rm, d));
      const float mn = fmaxf(mrun[mf][i], rm);
      const float alpha = fast_exp2(mrun[mf][i] - mn);
      mrun[mf][i] = mn;
      float s0 = 0.f;
#pragma unroll
      for (int nf = 0; nf < 4; ++nf) {
        const float p = fast_exp2(sc[mf][nf][i] - mn);
        sc[mf][nf][i] = p;
        s0 += p;
      }
#pragma unroll
      for (int d = 1; d < 16; d <<= 1) s0 += __shfl_xor(s0, d);
      lrun[mf][i] = lrun[mf][i] * alpha + s0;
#pragma unroll
      for (int nf = 0; nf < 4; ++nf) acc[mf][nf][i] *= alpha;
    }
  // ---- P: D-layout regs -> swizzled per-wave LDS (bf16) ----
#pragma unroll
  for (int mf = 0; mf < 2; ++mf)
#pragma unroll
    for (int nf = 0; nf < 4; ++nf)
#pragma unroll
      for (int i = 0; i < 4; ++i) {
        const int r = mf * 16 + lg * 4 + i;
        const int cbyte = (nf * 16 + lm) * 2;
        *(bf16_t*)(PsW + r * 128 + (cbyte ^ ((r & 7) << 4))) = (bf16_t)sc[mf][nf][i];
      }
  // ---- PV ----
#pragma unroll
  for (int kk = 0; kk < 2; ++kk) {
    bf16x8 pf[2];
#pragma unroll
    for (int mf = 0; mf < 2; ++mf) {
      const int r = mf * 16 + lm;
      pf[mf] = *(const bf16x8*)(PsW + r * 128 +
                                ((kk * 64 + lg * 16) ^ ((r & 7) << 4)));
    }
#pragma unroll
    for (int mf = 0; mf < 2; ++mf)
#pragma unroll
      for (int nf = 0; nf < 4; ++nf)
        acc[mf][nf] = __builtin_amdgcn_mfma_f32_16x16x32_bf16(pf[mf], vf.f[kk][nf],
                                                              acc[mf][nf], 0, 0, 0);
  }
}

__global__ __launch_bounds__(256) void flash_kernel(const bf16_t* __restrict__ q,
                                                    const bf16_t* __restrict__ k,
                                                    const bf16_t* __restrict__ vT,
                                                    bf16_t* __restrict__ o) {
  __shared__ __attribute__((aligned(16))) bf16_t Ps[4 * 32 * 64];
  // XCD-aware bijective swizzle: 512 blocks, 64 consecutive per XCD.
  const int wg = blockIdx.x;
  const int swz = (wg & 7) * 64 + (wg >> 3);
  const int qt = swz & 15, h = (swz >> 4) & 15, b = swz >> 8;
  const int tid = threadIdx.x;
  const int wave = tid >> 6, lane = tid & 63;
  const int lm = lane & 15, lg = lane >> 4;
  char* PsW = (char*)Ps + wave * 4096;

  const bf16_t* qb = q + (size_t)(b * SEQ + qt * 128 + wave * 32) * DM + h * DH;
  const bf16_t* kb = k + (size_t)b * SEQ * DM + h * DH;
  const bf16_t* vb = vT + (size_t)(b * NH + h) * DH * SEQ;

  // Q fragments in registers for the whole KV loop
  bf16x8 qf[2][2];
#pragma unroll
  for (int mf = 0; mf < 2; ++mf)
#pragma unroll
    for (int kk = 0; kk < 2; ++kk)
      qf[mf][kk] = *(const bf16x8*)(qb + (size_t)(mf * 16 + lm) * DM + kk * 32 + lg * 8);

  f32x4 acc[2][4];
  float mrun[2][4], lrun[2][4];
#pragma unroll
  for (int mf = 0; mf < 2; ++mf)
#pragma unroll
    for (int i = 0; i < 4; ++i) { mrun[mf][i] = -1e30f; lrun[mf][i] = 0.f; }
#pragma unroll
  for (int mf = 0; mf < 2; ++mf)
#pragma unroll
    for (int nf = 0; nf < 4; ++nf) acc[mf][nf] = (f32x4){0.f, 0.f, 0.f, 0.f};

  const int NT = SEQ / 64;  // 32
  Frags kfA, kfB;
  load_kf(kfA, kb, 0, lm, lg);
  for (int t = 0; t < NT; t += 2) {
    {
      Frags vf;
      load_vf(vf, vb, t, lm, lg);
      load_kf(kfB, kb, (t + 1 < NT) ? t + 1 : NT - 1, lm, lg);
      attn_iter(kfA, vf, qf, acc, mrun, lrun, PsW, lm, lg);
    }
    {
      Frags vf;
      load_vf(vf, vb, t + 1, lm, lg);
      load_kf(kfA, kb, (t + 2 < NT) ? t + 2 : NT - 1, lm, lg);
      attn_iter(kfB, vf, qf, acc, mrun, lrun, PsW, lm, lg);
    }
  }

  // ---- epilogue: O /= l, store bf16 ----
#pragma unroll
  for (int mf = 0; mf < 2; ++mf)
#pragma unroll
    for (int i = 0; i < 4; ++i) {
      const float inv = __builtin_amdgcn_rcpf(lrun[mf][i]);
      const int row = b * SEQ + qt * 128 + wave * 32 + mf * 16 + lg * 4 + i;
#pragma unroll
      for (int nf = 0; nf < 4; ++nf) {
        const int col = h * DH + nf * 16 + lm;
        o[(size_t)row * DM + col] = (bf16_t)(acc[mf][nf][i] * inv);
      }
    }
}

extern "C" void kernel_launch(void* const* d_in, const int* in_sizes, int n_in,
                              void* d_out, int out_size, void* d_ws, size_t ws_size,
                              hipStream_t stream) {
  (void)in_sizes; (void)n_in; (void)out_size; (void)ws_size;
  const float* Q  = (const float*)d_in[0];
  const float* Kx = (const float*)d_in[1];
  const float* V  = (const float*)d_in[2];
  const float* WQ = (const float*)d_in[3];
  const float* bQ = (const float*)d_in[4];
  const float* WK = (const float*)d_in[5];
  const float* bK = (const float*)d_in[6];
  const float* WV = (const float*)d_in[7];
  const float* bV = (const float*)d_in[8];
  const float* WO = (const float*)d_in[9];
  const float* bO = (const float*)d_in[10];

  const size_t MS  = (size_t)MR * DM;   // 4M elements
  const size_t WSZ = (size_t)DM * DM;   // 1M elements
  bf16_t* ws  = (bf16_t*)d_ws;
  bf16_t* Qb  = ws;
  bf16_t* Kb  = Qb + MS;
  bf16_t* Vb  = Kb + MS;
  bf16_t* WQt = Vb + MS;
  bf16_t* WKt = WQt + WSZ;
  bf16_t* WVt = WKt + WSZ;
  bf16_t* WOt = WVt + WSZ;
  bf16_t* qp  = WOt + WSZ;
  bf16_t* kp  = qp + MS;
  bf16_t* vp  = kp + MS;
  bf16_t* vTb = Qb;   // alias: Qb dead after q projection
  bf16_t* ao  = Kb;   // alias: Kb dead after k projection

  // fold score scale and log2(e) into the q projection -> softmax uses exp2
  const float scale_q = 0.125f * 1.44269504088896340736f;

  cvt_kernel<<<dim3((unsigned)(MS / 2048)), 256, 0, stream>>>(Q,  Qb, (int)MS);
  cvt_kernel<<<dim3((unsigned)(MS / 2048)), 256, 0, stream>>>(Kx, Kb, (int)MS);
  cvt_kernel<<<dim3((unsigned)(MS / 2048)), 256, 0, stream>>>(V,  Vb, (int)MS);
  wtrans_kernel<<<dim3(16, 16), 256, 0, stream>>>(WQ, WQt);
  wtrans_kernel<<<dim3(16, 16), 256, 0, stream>>>(WK, WKt);
  wtrans_kernel<<<dim3(16, 16), 256, 0, stream>>>(WV, WVt);
  wtrans_kernel<<<dim3(16, 16), 256, 0, stream>>>(WO, WOt);

  gemm_kernel<1><<<dim3(MR / 128, DM / 128), 256, 0, stream>>>(Qb, WQt, bQ, scale_q, qp, DM, DM);
  gemm_kernel<1><<<dim3(MR / 128, DM / 128), 256, 0, stream>>>(Kb, WKt, bK, 1.0f, kp, DM, DM);
  gemm_kernel<1><<<dim3(MR / 128, DM / 128), 256, 0, stream>>>(Vb, WVt, bV, 1.0f, vp, DM, DM);

  vtrans_kernel<<<dim3(SEQ / 64, NH, BATCH), 256, 0, stream>>>(vp, vTb);
  flash_kernel<<<dim3(512), 256, 0, stream>>>(qp, kp, vTb, ao);
  gemm_kernel<0><<<dim3(MR / 128, DM / 128), 256, 0, stream>>>(ao, WOt, bO, 1.0f, d_out, DM, DM);
}